// Round 1
// baseline (458.728 us; speedup 1.0000x reference)
//
#include <hip/hip_runtime.h>
#include <math.h>

#define TRI(i,j) (((i)*((i)+1))/2 + (j))

__device__ __forceinline__ float tanh_fast(float v) {
  v = fminf(fmaxf(v, -15.0f), 15.0f);
  float t = __expf(2.0f * v);                       // e^{2v}
  return fmaf(-2.0f, __builtin_amdgcn_rcpf(t + 1.0f), 1.0f);
}

// Pack per-hidden-unit records: [W1[0..7][j], b1[j], W2[j][0..5], pad] = 16 floats (64B)
__global__ void pack_weights(const float* __restrict__ W1,
                             const float* __restrict__ b1,
                             const float* __restrict__ W2,
                             float* __restrict__ wpk) {
  int j = threadIdx.x;   // 0..63
  float* r = wpk + (j << 4);
#pragma unroll
  for (int k = 0; k < 8; ++k) r[k] = W1[k * 64 + j];
  r[8] = b1[j];
#pragma unroll
  for (int i = 0; i < 6; ++i) r[9 + i] = W2[j * 6 + i];
  r[15] = 0.0f;
}

__launch_bounds__(256, 2)
__global__ void ukf_kernel(const float* __restrict__ gx,
                           const float* __restrict__ gP,
                           const float* __restrict__ gu,
                           const float* __restrict__ gy,
                           const float* __restrict__ gLQ,
                           const float* __restrict__ gLR,
                           const float* __restrict__ gb2,
                           const float* __restrict__ wpk,
                           float* __restrict__ out, int B) {
  __shared__ float lsm[256 * 37];   // per-thread 6x6 L, stride 37 (conflict-free)
  int b = blockIdx.x * blockDim.x + threadIdx.x;
  if (b >= B) return;
  float* Lsh = &lsm[threadIdx.x * 37];

  // ---- load per-batch inputs ----
  float x0[6];
  {
    const float* xb = gx + b * 6;
    float2 t0 = *(const float2*)(xb);
    float2 t1 = *(const float2*)(xb + 2);
    float2 t2 = *(const float2*)(xb + 4);
    x0[0]=t0.x; x0[1]=t0.y; x0[2]=t1.x; x0[3]=t1.y; x0[4]=t2.x; x0[5]=t2.y;
  }
  float2 uu = *(const float2*)(gu + b * 2);
  float yy0, yy1, yy2;
  { const float* yb = gy + b * 3; yy0 = yb[0]; yy1 = yb[1]; yy2 = yb[2]; }

  // ---- base = 0.75*(P+P^T) + 1e-5 I ; cholesky -> Lt (lower tri) ----
  float Lt[21];
  {
    float Pf[36];
    const float4* p4 = (const float4*)(gP + b * 36);
#pragma unroll
    for (int q = 0; q < 9; ++q) {
      float4 v = p4[q];
      Pf[q*4+0]=v.x; Pf[q*4+1]=v.y; Pf[q*4+2]=v.z; Pf[q*4+3]=v.w;
    }
    float base[21];
#pragma unroll
    for (int i = 0; i < 6; ++i)
#pragma unroll
      for (int j = 0; j <= i; ++j)
        base[TRI(i,j)] = 0.75f * (Pf[i*6+j] + Pf[j*6+i]) + ((i==j) ? 1e-5f : 0.0f);
#pragma unroll
    for (int k = 0; k < 6; ++k) {
      float s = base[TRI(k,k)];
#pragma unroll
      for (int m2 = 0; m2 < k; ++m2) s = fmaf(-Lt[TRI(k,m2)], Lt[TRI(k,m2)], s);
      float d = sqrtf(s);
      Lt[TRI(k,k)] = d;
      float inv = 1.0f / d;
#pragma unroll
      for (int i = k + 1; i < 6; ++i) {
        float s2 = base[TRI(i,k)];
#pragma unroll
        for (int m2 = 0; m2 < k; ++m2) s2 = fmaf(-Lt[TRI(i,m2)], Lt[TRI(k,m2)], s2);
        Lt[TRI(i,k)] = s2 * inv;
      }
    }
  }
  // stash full 6x6 L in LDS (upper = 0) so the sigma loop can index columns dynamically
#pragma unroll
  for (int i = 0; i < 6; ++i)
#pragma unroll
    for (int j = 0; j < 6; ++j)
      Lsh[i*6+j] = (j <= i) ? Lt[TRI(i,j)] : 0.0f;

  // ---- uniform small constants: Q, R, b2 (scalar-pipe loads) ----
  float Qm[21];
#pragma unroll
  for (int i = 0; i < 6; ++i)
#pragma unroll
    for (int j = 0; j <= i; ++j) {
      float s = (i==j) ? 1e-7f : 0.0f;
#pragma unroll
      for (int k = 0; k <= j; ++k) s = fmaf(gLQ[i*6+k], gLQ[j*6+k], s);
      Qm[TRI(i,j)] = s;
    }
  float Rm[6];
#pragma unroll
  for (int i = 0; i < 3; ++i)
#pragma unroll
    for (int j = 0; j <= i; ++j) {
      float s = (i==j) ? 1e-7f : 0.0f;
#pragma unroll
      for (int k = 0; k <= j; ++k) s = fmaf(gLR[i*3+k], gLR[j*3+k], s);
      Rm[TRI(i,j)] = s;
    }
  float b2r[6];
#pragma unroll
  for (int i = 0; i < 6; ++i) b2r[i] = gb2[i];

  // ---- UT accumulators ----
  float db[6] = {0,0,0,0,0,0};   // sum Wm * delta
  float cb[6] = {0,0,0,0,0,0};   // sum Wc * delta
  float U[21];
#pragma unroll
  for (int t = 0; t < 21; ++t) U[t] = 0.0f;

  float xin[8];
  xin[6] = uu.x; xin[7] = uu.y;

#pragma unroll 1
  for (int s = 0; s < 13; ++s) {
    float xs[6];
    if (s == 0) {
#pragma unroll
      for (int i = 0; i < 6; ++i) xs[i] = x0[i];
    } else {
      int   c   = (s <= 6) ? (s - 1) : (s - 7);
      float sgn = (s <= 6) ? 1.0f : -1.0f;
#pragma unroll
      for (int i = 0; i < 6; ++i) xs[i] = fmaf(sgn, Lsh[i*6+c], x0[i]);
    }
    // RK4
    float ksum[6]  = {0,0,0,0,0,0};
    float kprev[6] = {0,0,0,0,0,0};
#pragma unroll 1
    for (int st = 0; st < 4; ++st) {
      float cin = (st == 3) ? 0.01f : 0.005f;   // dt, dt/2 (st==0 nulled by kprev=0)
#pragma unroll
      for (int i = 0; i < 6; ++i) xin[i] = fmaf(cin, kprev[i], xs[i]);
      float acc0 = b2r[0], acc1 = b2r[1], acc2 = b2r[2],
            acc3 = b2r[3], acc4 = b2r[4], acc5 = b2r[5];
#pragma unroll 4
      for (int j = 0; j < 64; ++j) {
        const float* wr = wpk + (j << 4);       // uniform addr -> s_load_dwordx16
        float m0 = fmaf(xin[0], wr[0], xin[1] * wr[1]);
        float m1 = fmaf(xin[2], wr[2], xin[3] * wr[3]);
        float m2 = fmaf(xin[4], wr[4], xin[5] * wr[5]);
        float m3 = fmaf(xin[6], wr[6], fmaf(xin[7], wr[7], wr[8]));
        float h  = tanh_fast((m0 + m1) + (m2 + m3));
        acc0 = fmaf(h, wr[9],  acc0);
        acc1 = fmaf(h, wr[10], acc1);
        acc2 = fmaf(h, wr[11], acc2);
        acc3 = fmaf(h, wr[12], acc3);
        acc4 = fmaf(h, wr[13], acc4);
        acc5 = fmaf(h, wr[14], acc5);
      }
      float wks = (st == 0 || st == 3) ? 1.0f : 2.0f;
      kprev[0]=acc0; kprev[1]=acc1; kprev[2]=acc2; kprev[3]=acc3; kprev[4]=acc4; kprev[5]=acc5;
#pragma unroll
      for (int i = 0; i < 6; ++i) ksum[i] = fmaf(wks, kprev[i], ksum[i]);
    }
    float wm = (s == 0) ? -3.0f   : (1.0f/3.0f);
    float wc = (s == 0) ? -0.25f  : (1.0f/3.0f);
    float dl[6];
#pragma unroll
    for (int i = 0; i < 6; ++i) {
      float sp = fmaf(0.01f/6.0f, ksum[i], xs[i]);  // sigma_pred
      dl[i] = sp - x0[i];                            // delta vs prior x
    }
#pragma unroll
    for (int i = 0; i < 6; ++i) {
      db[i] = fmaf(wm, dl[i], db[i]);
      float wd = wc * dl[i];
      cb[i] += wd;
#pragma unroll
      for (int j = 0; j <= i; ++j) U[TRI(i,j)] = fmaf(wd, dl[j], U[TRI(i,j)]);
    }
  }

  // ---- moments -> D = sum Wc dx dx^T ----
  float xp[6];
#pragma unroll
  for (int i = 0; i < 6; ++i) xp[i] = x0[i] + db[i];
  float D[21];
#pragma unroll
  for (int i = 0; i < 6; ++i)
#pragma unroll
    for (int j = 0; j <= i; ++j) {
      float v = U[TRI(i,j)];
      v -= cb[i] * db[j];
      v -= db[i] * cb[j];
      v = fmaf(3.75f * db[i], db[j], v);   // sum(Wc) = 3.75
      D[TRI(i,j)] = v;
    }

  // ---- S = D[:3,:3] + R ; inverse of S+1e-5 I via adjugate ----
  float s00 = D[TRI(0,0)] + Rm[TRI(0,0)];
  float s10 = D[TRI(1,0)] + Rm[TRI(1,0)];
  float s11 = D[TRI(1,1)] + Rm[TRI(1,1)];
  float s20 = D[TRI(2,0)] + Rm[TRI(2,0)];
  float s21 = D[TRI(2,1)] + Rm[TRI(2,1)];
  float s22 = D[TRI(2,2)] + Rm[TRI(2,2)];
  float a00 = s00 + 1e-5f, a11 = s11 + 1e-5f, a22 = s22 + 1e-5f;
  float a10 = s10, a20 = s20, a21 = s21;
  float adj00 = a11*a22 - a21*a21;
  float adj01 = a20*a21 - a10*a22;
  float adj02 = a10*a21 - a11*a20;
  float adj11 = a00*a22 - a20*a20;
  float adj12 = a10*a20 - a00*a21;
  float adj22 = a00*a11 - a10*a10;
  float det  = a00*adj00 + a10*adj01 + a20*adj02;
  float idet = 1.0f / det;
  float I00 = adj00*idet, I01 = adj01*idet, I02 = adj02*idet;
  float I11 = adj11*idet, I12 = adj12*idet, I22 = adj22*idet;

#define DS(i,j) ((i) >= (j) ? D[TRI(i,j)] : D[TRI(j,i)])
  float K_[18];
#pragma unroll
  for (int i = 0; i < 6; ++i) {
    float c0 = DS(i,0), c1 = DS(i,1), c2 = DS(i,2);   // cross = D[:, :3]
    K_[i*3+0] = c0*I00 + c1*I01 + c2*I02;
    K_[i*3+1] = c0*I01 + c1*I11 + c2*I12;
    K_[i*3+2] = c0*I02 + c1*I12 + c2*I22;
  }
  float inn0 = yy0 - xp[0], inn1 = yy1 - xp[1], inn2 = yy2 - xp[2];
  float xu[6];
#pragma unroll
  for (int i = 0; i < 6; ++i)
    xu[i] = xp[i] + K_[i*3]*inn0 + K_[i*3+1]*inn1 + K_[i*3+2]*inn2;

  float KS[18];
#pragma unroll
  for (int i = 0; i < 6; ++i) {
    float k0 = K_[i*3], k1 = K_[i*3+1], k2 = K_[i*3+2];
    KS[i*3+0] = k0*s00 + k1*s10 + k2*s20;
    KS[i*3+1] = k0*s10 + k1*s11 + k2*s21;
    KS[i*3+2] = k0*s20 + k1*s21 + k2*s22;
  }
  float Pu[21];
#pragma unroll
  for (int i = 0; i < 6; ++i)
#pragma unroll
    for (int j = 0; j <= i; ++j) {
      float v = D[TRI(i,j)] + Qm[TRI(i,j)];   // P_pred
      v -= KS[i*3]*K_[j*3] + KS[i*3+1]*K_[j*3+1] + KS[i*3+2]*K_[j*3+2];
      Pu[TRI(i,j)] = v + ((i==j) ? 1e-4f : 0.0f);
    }

  // ---- stores ----
  float* o_xu = out;
  float* o_Pu = out + (size_t)6  * B;
  float* o_xp = out + (size_t)42 * B;
  float* o_Pp = out + (size_t)48 * B;
  float* o_yp = out + (size_t)84 * B;
  float* o_S  = out + (size_t)87 * B;
  float* o_K  = out + (size_t)96 * B;

  {
    float* p = o_xu + b * 6;
    ((float2*)p)[0] = make_float2(xu[0], xu[1]);
    ((float2*)p)[1] = make_float2(xu[2], xu[3]);
    ((float2*)p)[2] = make_float2(xu[4], xu[5]);
  }
  {
    float* p = o_Pu + b * 36;
#pragma unroll
    for (int i = 0; i < 6; ++i)
#pragma unroll
      for (int j = 0; j < 6; j += 2) {
        float v0 = (i>=j)   ? Pu[TRI(i,j)]   : Pu[TRI(j,i)];
        float v1 = (i>=j+1) ? Pu[TRI(i,j+1)] : Pu[TRI(j+1,i)];
        *(float2*)(p + i*6 + j) = make_float2(v0, v1);
      }
  }
  {
    float* p = o_xp + b * 6;
    ((float2*)p)[0] = make_float2(xp[0], xp[1]);
    ((float2*)p)[1] = make_float2(xp[2], xp[3]);
    ((float2*)p)[2] = make_float2(xp[4], xp[5]);
  }
  {
    float* p = o_Pp + b * 36;
#pragma unroll
    for (int i = 0; i < 6; ++i)
#pragma unroll
      for (int j = 0; j < 6; j += 2) {
        float v0 = ((i>=j)   ? D[TRI(i,j)]   : D[TRI(j,i)])   + ((i>=j)   ? Qm[TRI(i,j)]   : Qm[TRI(j,i)]);
        float v1 = ((i>=j+1) ? D[TRI(i,j+1)] : D[TRI(j+1,i)]) + ((i>=j+1) ? Qm[TRI(i,j+1)] : Qm[TRI(j+1,i)]);
        *(float2*)(p + i*6 + j) = make_float2(v0, v1);
      }
  }
  {
    float* p = o_yp + b * 3;
    p[0] = xp[0]; p[1] = xp[1]; p[2] = xp[2];
  }
  {
    float* p = o_S + b * 9;
    p[0]=s00; p[1]=s10; p[2]=s20;
    p[3]=s10; p[4]=s11; p[5]=s21;
    p[6]=s20; p[7]=s21; p[8]=s22;
  }
  {
    float* p = o_K + b * 18;
#pragma unroll
    for (int i = 0; i < 9; ++i)
      ((float2*)p)[i] = make_float2(K_[i*2], K_[i*2+1]);
  }
}

extern "C" void kernel_launch(void* const* d_in, const int* in_sizes, int n_in,
                              void* d_out, int out_size, void* d_ws, size_t ws_size,
                              hipStream_t stream) {
  const float* x  = (const float*)d_in[0];
  const float* P  = (const float*)d_in[1];
  const float* u  = (const float*)d_in[2];
  const float* y  = (const float*)d_in[3];
  const float* LQ = (const float*)d_in[4];
  const float* LR = (const float*)d_in[5];
  const float* W1 = (const float*)d_in[6];
  const float* b1 = (const float*)d_in[7];
  const float* W2 = (const float*)d_in[8];
  const float* b2 = (const float*)d_in[9];
  float* out = (float*)d_out;
  float* wpk = (float*)d_ws;
  int B = in_sizes[0] / 6;

  hipLaunchKernelGGL(pack_weights, dim3(1), dim3(64), 0, stream, W1, b1, W2, wpk);
  int block = 256;
  int grid  = (B + block - 1) / block;
  hipLaunchKernelGGL(ukf_kernel, dim3(grid), dim3(block), 0, stream,
                     x, P, u, y, LQ, LR, b2, wpk, out, B);
}